// Round 2
// baseline (302.541 us; speedup 1.0000x reference)
//
#include <hip/hip_runtime.h>

#define EPSBN 1e-5f

typedef _Float16 f16;
typedef _Float16 f16x8 __attribute__((ext_vector_type(8)));
typedef _Float16 f16x4 __attribute__((ext_vector_type(4)));
typedef _Float16 f16x2 __attribute__((ext_vector_type(2)));
typedef float    f32x4 __attribute__((ext_vector_type(4)));

__device__ inline unsigned int pack2(float a, float b) {
    union { f16x2 h; unsigned int u; } cv;
    cv.h[0] = (f16)a; cv.h[1] = (f16)b;
    return cv.u;
}
__device__ inline f16x4 hmax4(f16x4 a, f16x4 b) {
    f16x4 r;
    #pragma unroll
    for (int i = 0; i < 4; ++i) r[i] = a[i] > b[i] ? a[i] : b[i];
    return r;
}
__device__ inline f16x8 relu8(f16x8 v) {
    f16x8 r;
    #pragma unroll
    for (int i = 0; i < 8; ++i) r[i] = v[i] > (f16)0.f ? v[i] : (f16)0.f;
    return r;
}

// ---------------------------------------------------------------------------
// wprep: weights -> f16.  fc1w [0,32768) ; w1 [32768,40960) ;
// w2 as [tau][o][i] [40960,53248) ; w3 [53248,61440)
// ---------------------------------------------------------------------------
__global__ void wprep_kernel(const float* __restrict__ fc1w,
                             const float* __restrict__ w1,
                             const float* __restrict__ w2,
                             const float* __restrict__ w3,
                             f16* __restrict__ dst) {
    const int i = blockIdx.x * 256 + threadIdx.x;   // 61440 total
    float v;
    if (i < 32768)      v = fc1w[i];
    else if (i < 40960) v = w1[i - 32768];
    else if (i < 53248) {
        const int j = i - 40960, tau = j >> 12, rest = j & 4095;
        v = w2[rest * 3 + tau];
    } else              v = w3[i - 53248];
    dst[i] = (f16)v;
}

// ---------------------------------------------------------------------------
// fc1 v3: counted-vmcnt deep pipeline (T3+T4).
//
// v2 (66 us) issued next-stage loads then hit __syncthreads -> compiler
// s_waitcnt vmcnt(0) -> prefetch depth ~0, per-stage exposed latency, HBM
// never saturated (stage period 19.8k cy vs 6.4k at BW share).
// v3: ring of 4 half-buffers (16 ch each), horizon = 3 halves (~2 stage
// periods in flight, 48 KB/block continuous), raw s_barrier + inline-asm
// s_waitcnt vmcnt(2) (vmcnt(0) only for the last stage), sched_barrier(0)
// fences (rule #18).  Everything else (tiling, frag build, epilogue)
// unchanged from v2.  LDS 69.6 KB -> 2 blocks/CU.
// ---------------------------------------------------------------------------
__global__ __launch_bounds__(512, 4)
void fc1_mfma(const float* __restrict__ feat,   // [8][256][16384] f32
              const f16*   __restrict__ w16,    // [128][256] f16
              const float* __restrict__ bias,   // [128]
              f16*         __restrict__ xmap) { // [8][16384][128] f16
    __shared__ union {
        float hb[4][4176];            // 4 half-buffers: 16 ch, row r at r*260+(r>>3)*16
        f16   epi[256][136];          // 69632 B epilogue staging
    } u;

    const int tid  = threadIdx.x;
    const int wv   = tid >> 6, lane = tid & 63;
    const int n16  = lane & 15, quad = lane >> 4;
    const int img  = blockIdx.x & 7;              // XCD pin (same as loi)
    const int p0   = (blockIdx.x >> 3) << 8;      // 256-pt tile

    const float* fimg = feat + (((size_t)img) << 22);

    f32x4 acc[8][2];
    #pragma unroll
    for (int ot = 0; ot < 8; ++ot) {
        acc[ot][0] = (f32x4){0.f, 0.f, 0.f, 0.f};
        acc[ot][1] = (f32x4){0.f, 0.f, 0.f, 0.f};
    }

    // issue one HALF-stage (16 channels) of contiguous 1 KB rows into ring slot h&3
    auto issue = [&](int h) {
        float* base = u.hb[h & 3];
        #pragma unroll
        for (int i = 0; i < 2; ++i) {
            const int cl = wv * 2 + i;            // local channel 0..15
            const int ch = h * 16 + cl;
            const float* src = fimg + (((size_t)ch) << 14) + p0 + lane * 4;
            float* dst = base + cl * 260 + (cl >> 3) * 16;   // wave-uniform base
            __builtin_amdgcn_global_load_lds(
                (const __attribute__((address_space(1))) void*)src,
                (__attribute__((address_space(3))) void*)dst, 16, 0, 0);
        }
    };

    // prologue: 3 halves in flight (6 loads/thread)
    issue(0); issue(1); issue(2);

    #pragma unroll
    for (int s = 0; s < 8; ++s) {
        // halves 2s, 2s+1 must be complete; half 2s+2 may stay in flight
        if (s < 7) asm volatile("s_waitcnt vmcnt(2)" ::: "memory");
        else       asm volatile("s_waitcnt vmcnt(0)" ::: "memory");
        __builtin_amdgcn_s_barrier();
        __builtin_amdgcn_sched_barrier(0);
        asm volatile("" ::: "memory");

        const float* bufA = u.hb[(2 * s) & 3];        // k local 0..15
        const float* bufB = u.hb[(2 * s + 1) & 3];    // k local 16..31

        // B-frags (x): lane(n16,quad) holds x[k=quad*8+j][pt=base+n16]
        f16x8 xf[2];
        #pragma unroll
        for (int pt = 0; pt < 2; ++pt) {
            const int pbase = wv * 32 + pt * 16 + n16;
            const float* fb = ((quad & 2) ? bufB : bufA)
                              + (quad & 1) * (8 * 260 + 16) + pbase;
            f16x8 xv;
            #pragma unroll
            for (int j = 0; j < 8; ++j)
                xv[j] = (f16)fb[j * 260];
            xf[pt] = xv;
        }

        // A-frags (W, L2-hot): lane(n16,quad) holds W[o=ot*16+n16][k=quad*8+j]
        const f16* wrow = w16 + (size_t)n16 * 256 + s * 32 + quad * 8;
        #pragma unroll
        for (int ot = 0; ot < 8; ++ot) {
            const f16x8 wf = *(const f16x8*)(wrow + ot * 4096);
            acc[ot][0] = __builtin_amdgcn_mfma_f32_16x16x32_f16(wf, xf[0], acc[ot][0], 0, 0, 0);
            acc[ot][1] = __builtin_amdgcn_mfma_f32_16x16x32_f16(wf, xf[1], acc[ot][1], 0, 0, 0);
        }

        __builtin_amdgcn_sched_barrier(0);
        __builtin_amdgcn_s_barrier();       // all waves done reading bufs (2s,2s+1)&3
        __builtin_amdgcn_sched_barrier(0);

        if (2 * s + 3 < 16) issue(2 * s + 3);   // refill freed ring slots
        if (2 * s + 4 < 16) issue(2 * s + 4);
    }

    __builtin_amdgcn_sched_barrier(0);
    asm volatile("" ::: "memory");

    // epilogue: D[o][pt] row = quad*4+r (o), col = n16 (pt) -> LDS -> coalesced rows
    #pragma unroll
    for (int ot = 0; ot < 8; ++ot) {
        const float4 bq = *(const float4*)&bias[ot * 16 + quad * 4];
        const float bqa[4] = {bq.x, bq.y, bq.z, bq.w};
        #pragma unroll
        for (int pt = 0; pt < 2; ++pt) {
            f16x4 h;
            #pragma unroll
            for (int r = 0; r < 4; ++r) h[r] = (f16)(acc[ot][pt][r] + bqa[r]);
            *(f16x4*)&u.epi[wv * 32 + pt * 16 + n16][ot * 16 + quad * 4] = h;
        }
    }
    __syncthreads();

    #pragma unroll
    for (int it = 0; it < 8; ++it) {
        const int idx = it * 512 + tid;
        const int row = idx >> 4, seg = idx & 15;
        const float4 v = *(const float4*)&u.epi[row][seg * 8];
        *(float4*)&xmap[(((size_t)(img * 16384 + p0 + row)) << 7) + seg * 8] = v;
    }
}

// ---------------------------------------------------------------------------
// loi: 8 lines/block, image = blockIdx & 7 (XCD-pinned: gathers stay in the
// XCD L2 that fc1 just filled).  Sampling in packed f16 (4 ch/lane, 8B loads)
// -> xp[64n][128c] f16 -> conv1/conv2/conv3 MFMA -> residual+relu+fc2.
// ---------------------------------------------------------------------------
__global__ __launch_bounds__(256)
void loi_kernel(const f16*   __restrict__ x,       // [8][16384][128] f16
                const float* __restrict__ lines,
                const f16*   __restrict__ wsp,
                const float* __restrict__ bn1g, const float* __restrict__ bn1b,
                const float* __restrict__ bn1m, const float* __restrict__ bn1v,
                const float* __restrict__ b1,
                const float* __restrict__ bn2g, const float* __restrict__ bn2b,
                const float* __restrict__ bn2m, const float* __restrict__ bn2v,
                const float* __restrict__ b2,
                const float* __restrict__ bn3g, const float* __restrict__ bn3b,
                const float* __restrict__ bn3m, const float* __restrict__ bn3v,
                const float* __restrict__ b3,
                const float* __restrict__ fc2w, const float* __restrict__ fc2b,
                float* __restrict__ out) {
    __shared__ f16 xp[64][136];                       // 17408 B
    __shared__ alignas(16) union {
        struct { int toff[256][4]; f16 twgt[256][4]; } tp;     // 6144 B
        struct { f16 h1[80][72]; f16 h2[64][72]; } cv;         // 20736 B
    } u;
    __shared__ f16 s1h[128], t1h[128];                // 512 B
    __shared__ float s2f[64], t2f[64], s3f[64], t3f[64], b1f[64], b2f[64];
    __shared__ float b3f[128];
    __shared__ float wsum[4][8];

    const f16* w1f16 = wsp + 32768;
    const f16* w2f16 = wsp + 40960;
    const f16* w3f16 = wsp + 53248;

    const int tid  = threadIdx.x;
    const int wv   = tid >> 6, lane = tid & 63;
    const int n16  = lane & 15, quad = lane >> 4;
    const int img  = blockIdx.x & 7;                  // XCD swizzle
    const int mblk = blockIdx.x >> 3;                 // 0..255 within image

    // ---- LUTs ----
    if (tid < 128) {
        const float s = bn1g[tid] * rsqrtf(bn1v[tid] + EPSBN);
        s1h[tid] = (f16)s; t1h[tid] = (f16)(bn1b[tid] - bn1m[tid] * s);
    }
    if (tid < 64) {
        const float s = bn2g[tid] * rsqrtf(bn2v[tid] + EPSBN);
        s2f[tid] = s; t2f[tid] = bn2b[tid] - bn2m[tid] * s;
        b1f[tid] = b1[tid];
    } else if (tid < 128) {
        const int c = tid - 64;
        const float s = bn3g[c] * rsqrtf(bn3v[c] + EPSBN);
        s3f[c] = s; t3f[c] = bn3b[c] - bn3m[c] * s;
        b2f[c] = b2[c];
    } else {
        b3f[tid - 128] = b3[tid - 128];
    }

    // ---- interp tuples: one per (line, pt) ----
    {
        const int li = tid >> 5, pt = tid & 31;
        const int gl = img * 2048 + mblk * 8 + li;
        const float4 ln = *(const float4*)&lines[gl * 4];
        const float lam = (float)pt * (1.0f / 31.0f);
        const float px = ln.x * lam + ln.z * (1.f - lam) - 0.5f;
        const float py = ln.y * lam + ln.w * (1.f - lam) - 0.5f;
        const float px0 = fminf(fmaxf(floorf(px), 0.f), 127.f);
        const float py0 = fminf(fmaxf(floorf(py), 0.f), 127.f);
        const float px1 = fminf(px0 + 1.f, 127.f);
        const float py1 = fminf(py0 + 1.f, 127.f);
        const int ix0 = (int)px0, iy0 = (int)py0;
        const int ix1 = (int)px1, iy1 = (int)py1;
        u.tp.toff[tid][0] = (((ix0 << 7) + iy0) << 7);
        u.tp.toff[tid][1] = (((ix1 << 7) + iy0) << 7);
        u.tp.toff[tid][2] = (((ix0 << 7) + iy1) << 7);
        u.tp.toff[tid][3] = (((ix1 << 7) + iy1) << 7);
        const float wx1 = px1 - px, wx0 = px - px0;
        const float wy1 = py1 - py, wy0 = py - py0;
        u.tp.twgt[tid][0] = (f16)(wx1 * wy1); u.tp.twgt[tid][1] = (f16)(wx0 * wy1);
        u.tp.twgt[tid][2] = (f16)(wx1 * wy0); u.tp.twgt[tid][3] = (f16)(wx0 * wy0);
    }
    __syncthreads();   // B1

    // ---- sampling + maxpool, packed f16: lane -> 4 channels, half-wave -> line ----
    {
        const int h = lane >> 5, j = lane & 31;     // line parity, channel group
        const int li = wv * 2 + h;
        const f16* xbh = x + (((size_t)img) << 21) + 4 * j;
        #pragma unroll
        for (int t = 0; t < 8; ++t) {
            f16x4 m = {(f16)(-60000.f), (f16)(-60000.f), (f16)(-60000.f), (f16)(-60000.f)};
            #pragma unroll
            for (int s = 0; s < 4; ++s) {
                const int combo = li * 32 + t * 4 + s;
                const int4  off = *(const int4*)&u.tp.toff[combo][0];
                const f16x4 tw  = *(const f16x4*)&u.tp.twgt[combo][0];
                const f16x4 g00 = *(const f16x4*)(xbh + off.x);
                const f16x4 g10 = *(const f16x4*)(xbh + off.y);
                const f16x4 g01 = *(const f16x4*)(xbh + off.z);
                const f16x4 g11 = *(const f16x4*)(xbh + off.w);
                const f16x4 w0 = {tw[0], tw[0], tw[0], tw[0]};
                const f16x4 w1v = {tw[1], tw[1], tw[1], tw[1]};
                const f16x4 w2v = {tw[2], tw[2], tw[2], tw[2]};
                const f16x4 w3v = {tw[3], tw[3], tw[3], tw[3]};
                f16x4 v = g00 * w0 + g10 * w1v + g01 * w2v + g11 * w3v;
                m = hmax4(m, v);
            }
            *(f16x4*)&xp[li * 8 + t][4 * j] = m;
        }
    }
    __syncthreads();   // B2 (tuples dead; xp ready)

    // ---- zero h1 guard rows ----
    {
        const int r = tid >> 4, seg = tid & 15;
        const int row = (r >> 1) * 10 + (r & 1) * 9;
        *(unsigned long long*)&u.cv.h1[row][seg * 4] = 0ull;
    }

    // ---- conv1 + fused bn1/relu (packed f16) ----
    {
        const int o_lane = wv * 16 + n16;
        f32x4 acc1[4];
        #pragma unroll
        for (int nt = 0; nt < 4; ++nt) acc1[nt] = (f32x4){0.f, 0.f, 0.f, 0.f};
        #pragma unroll
        for (int ks = 0; ks < 4; ++ks) {
            const int k = ks * 32 + quad * 8;
            const f16x8 a  = *(const f16x8*)&w1f16[o_lane * 128 + k];
            const f16x8 s8 = *(const f16x8*)&s1h[k];
            const f16x8 t8 = *(const f16x8*)&t1h[k];
            #pragma unroll
            for (int nt = 0; nt < 4; ++nt) {
                const f16x8 raw = *(const f16x8*)&xp[nt * 16 + n16][k];
                const f16x8 bf = relu8(raw * s8 + t8);
                acc1[nt] = __builtin_amdgcn_mfma_f32_16x16x32_f16(a, bf, acc1[nt], 0, 0, 0);
            }
        }
        #pragma unroll
        for (int nt = 0; nt < 4; ++nt) {
            const int n = nt * 16 + n16;
            const int nprow = (n >> 3) * 10 + (n & 7) + 1;
            #pragma unroll
            for (int r = 0; r < 4; ++r) {
                const int o = wv * 16 + quad * 4 + r;
                const float v = fmaxf((acc1[nt][r] + b1f[o]) * s2f[o] + t2f[o], 0.f);
                u.cv.h1[nprow][o] = (f16)v;
            }
        }
    }
    __syncthreads();   // B3

    // ---- conv2: 3 shifted [64x64] matmuls ----
    {
        const int o_lane = wv * 16 + n16;
        f32x4 acc2[4];
        #pragma unroll
        for (int nt = 0; nt < 4; ++nt) acc2[nt] = (f32x4){0.f, 0.f, 0.f, 0.f};
        #pragma unroll
        for (int d = 0; d < 3; ++d) {
            const f16* A2 = w2f16 + d * 4096;
            #pragma unroll
            for (int ks = 0; ks < 2; ++ks) {
                const int k = ks * 32 + quad * 8;
                const f16x8 a = *(const f16x8*)&A2[o_lane * 64 + k];
                #pragma unroll
                for (int nt = 0; nt < 4; ++nt) {
                    const int n = nt * 16 + n16;
                    const int row = (n >> 3) * 10 + (n & 7) + d;
                    const f16x8 bf = *(const f16x8*)&u.cv.h1[row][k];
                    acc2[nt] = __builtin_amdgcn_mfma_f32_16x16x32_f16(a, bf, acc2[nt], 0, 0, 0);
                }
            }
        }
        #pragma unroll
        for (int nt = 0; nt < 4; ++nt) {
            const int n = nt * 16 + n16;
            #pragma unroll
            for (int r = 0; r < 4; ++r) {
                const int o = wv * 16 + quad * 4 + r;
                const float v = fmaxf((acc2[nt][r] + b2f[o]) * s3f[o] + t3f[o], 0.f);
                u.cv.h2[n][o] = (f16)v;
            }
        }
    }
    __syncthreads();   // B4

    // ---- conv3 + residual + relu + fc2 ----
    {
        // per-lane fc2 weights: (n&7) == n16&7 is lane-constant -> 8 scalars
        const int col = n16 & 7, obase = wv * 16 + quad * 4;
        float fcv[2][4];
        #pragma unroll
        for (int h = 0; h < 2; ++h)
            #pragma unroll
            for (int r = 0; r < 4; ++r)
                fcv[h][r] = fc2w[(h * 64 + obase + r) * 8 + col];

        f32x4 acc3[2][4];
        #pragma unroll
        for (int h = 0; h < 2; ++h)
            #pragma unroll
            for (int nt = 0; nt < 4; ++nt) acc3[h][nt] = (f32x4){0.f, 0.f, 0.f, 0.f};
        #pragma unroll
        for (int ks = 0; ks < 2; ++ks) {
            const int k = ks * 32 + quad * 8;
            const f16x8 a0 = *(const f16x8*)&w3f16[(wv * 16 + n16) * 64 + k];
            const f16x8 a1 = *(const f16x8*)&w3f16[(64 + wv * 16 + n16) * 64 + k];
            #pragma unroll
            for (int nt = 0; nt < 4; ++nt) {
                const f16x8 bf = *(const f16x8*)&u.cv.h2[nt * 16 + n16][k];
                acc3[0][nt] = __builtin_amdgcn_mfma_f32_16x16x32_f16(a0, bf, acc3[0][nt], 0, 0, 0);
                acc3[1][nt] = __builtin_amdgcn_mfma_f32_16x16x32_f16(a1, bf, acc3[1][nt], 0, 0, 0);
            }
        }
        float part[4] = {0.f, 0.f, 0.f, 0.f};
        #pragma unroll
        for (int h = 0; h < 2; ++h) {
            const float4 bq = *(const float4*)&b3f[h * 64 + obase];
            const float bqa[4] = {bq.x, bq.y, bq.z, bq.w};
            #pragma unroll
            for (int nt = 0; nt < 4; ++nt) {
                const int n = nt * 16 + n16;
                const f16x4 rx = *(const f16x4*)&xp[n][h * 64 + obase];
                float p = 0.f;
                #pragma unroll
                for (int r = 0; r < 4; ++r) {
                    float v = acc3[h][nt][r] + bqa[r] + (float)rx[r];
                    v = fmaxf(v, 0.f);
                    p += v * fcv[h][r];
                }
                part[nt] += p;
            }
        }
        #pragma unroll
        for (int off_i = 0; off_i < 5; ++off_i) {
            const int off = (int[]){1, 2, 4, 16, 32}[off_i];
            part[0] += __shfl_xor(part[0], off, 64);
            part[1] += __shfl_xor(part[1], off, 64);
            part[2] += __shfl_xor(part[2], off, 64);
            part[3] += __shfl_xor(part[3], off, 64);
        }
        if ((lane & 55) == 0) {          // lanes 0 and 8
            const int par = (lane >> 3) & 1;
            wsum[wv][0 + par] = part[0];
            wsum[wv][2 + par] = part[1];
            wsum[wv][4 + par] = part[2];
            wsum[wv][6 + par] = part[3];
        }
    }
    __syncthreads();   // B5

    if (tid < 8) {
        const float s = wsum[0][tid] + wsum[1][tid] + wsum[2][tid] + wsum[3][tid];
        out[img * 2048 + mblk * 8 + tid] = s + fc2b[0];
    }
}

// ---------------------------------------------------------------------------
extern "C" void kernel_launch(void* const* d_in, const int* in_sizes, int n_in,
                              void* d_out, int out_size, void* d_ws, size_t ws_size,
                              hipStream_t stream) {
    const float* feature = (const float*)d_in[0];
    const float* lines   = (const float*)d_in[1];
    const float* fc1_w   = (const float*)d_in[2];
    const float* fc1_b   = (const float*)d_in[3];
    const float* bn1g    = (const float*)d_in[4];
    const float* bn1b    = (const float*)d_in[5];
    const float* bn1m    = (const float*)d_in[6];
    const float* bn1v    = (const float*)d_in[7];
    const float* w1      = (const float*)d_in[8];
    const float* b1      = (const float*)d_in[9];
    const float* bn2g    = (const float*)d_in[10];
    const float* bn2b    = (const float*)d_in[11];
    const float* bn2m    = (const float*)d_in[12];
    const float* bn2v    = (const float*)d_in[13];
    const float* w2      = (const float*)d_in[14];
    const float* b2      = (const float*)d_in[15];
    const float* bn3g    = (const float*)d_in[16];
    const float* bn3b    = (const float*)d_in[17];
    const float* bn3m    = (const float*)d_in[18];
    const float* bn3v    = (const float*)d_in[19];
    const float* w3      = (const float*)d_in[20];
    const float* b3      = (const float*)d_in[21];
    const float* fc2w    = (const float*)d_in[22];
    const float* fc2b    = (const float*)d_in[23];

    f16* xmap = (f16*)d_ws;                                      // 32 MiB
    f16* wsp  = (f16*)((char*)d_ws + (size_t)32 * 1024 * 1024);  // 120 KiB

    wprep_kernel<<<240, 256, 0, stream>>>(fc1_w, w1, w2, w3, wsp);
    fc1_mfma<<<512, 512, 0, stream>>>(feature, wsp, fc1_b, xmap);
    loi_kernel<<<2048, 256, 0, stream>>>(xmap, lines, wsp,
                                         bn1g, bn1b, bn1m, bn1v, b1,
                                         bn2g, bn2b, bn2m, bn2v, b2,
                                         bn3g, bn3b, bn3m, bn3v, b3,
                                         fc2w, fc2b, (float*)d_out);
}

// Round 4
// 285.554 us; speedup vs baseline: 1.0595x; 1.0595x over previous
//
#include <hip/hip_runtime.h>

#define EPSBN 1e-5f

typedef _Float16 f16;
typedef _Float16 f16x8 __attribute__((ext_vector_type(8)));
typedef _Float16 f16x4 __attribute__((ext_vector_type(4)));
typedef _Float16 f16x2 __attribute__((ext_vector_type(2)));
typedef float    f32x4 __attribute__((ext_vector_type(4)));

__device__ inline unsigned int pack2(float a, float b) {
    union { f16x2 h; unsigned int u; } cv;
    cv.h[0] = (f16)a; cv.h[1] = (f16)b;
    return cv.u;
}
__device__ inline f16x8 hmax8(f16x8 a, f16x8 b) {
    f16x8 r;
    #pragma unroll
    for (int i = 0; i < 8; ++i) r[i] = a[i] > b[i] ? a[i] : b[i];
    return r;
}
__device__ inline f16x8 relu8(f16x8 v) {
    f16x8 r;
    #pragma unroll
    for (int i = 0; i < 8; ++i) r[i] = v[i] > (f16)0.f ? v[i] : (f16)0.f;
    return r;
}

// ---------------------------------------------------------------------------
// wprep: weights -> f16.  fc1w [0,32768) ; w1 [32768,40960) ;
// w2 as [tau][o][i] [40960,53248) ; w3 [53248,61440)
// ---------------------------------------------------------------------------
__global__ void wprep_kernel(const float* __restrict__ fc1w,
                             const float* __restrict__ w1,
                             const float* __restrict__ w2,
                             const float* __restrict__ w3,
                             f16* __restrict__ dst) {
    const int i = blockIdx.x * 256 + threadIdx.x;   // 61440 total
    float v;
    if (i < 32768)      v = fc1w[i];
    else if (i < 40960) v = w1[i - 32768];
    else if (i < 53248) {
        const int j = i - 40960, tau = j >> 12, rest = j & 4095;
        v = w2[rest * 3 + tau];
    } else              v = w3[i - 53248];
    dst[i] = (f16)v;
}

// ---------------------------------------------------------------------------
// fc1 v2 (reverted from v3): 256-point tiles, contiguous 1 KB channel-row
// streaming via global_load_lds_dwordx4, double-buffered with __syncthreads.
// v3's counted-vmcnt ring regressed (75 vs 66 us): the W-fragment global
// loads inside the MFMA section also count in vmcnt, so the compiler's
// pre-MFMA waits drained the DMA ring every stage anyway -> v3 = v2 + extra
// barrier overhead.  Keeping the measured-best v2 structure.
// ---------------------------------------------------------------------------
__global__ __launch_bounds__(512, 4)
void fc1_mfma(const float* __restrict__ feat,   // [8][256][16384] f32
              const f16*   __restrict__ w16,    // [128][256] f16
              const float* __restrict__ bias,   // [128]
              f16*         __restrict__ xmap) { // [8][16384][128] f16
    __shared__ union {
        float fbuf[2][8368];          // 2 x 33472 B: 32 ch x 260 dw (+16 dw per 8-ch group)
        f16   epi[256][136];          // 69632 B epilogue staging
    } u;

    const int tid  = threadIdx.x;
    const int wv   = tid >> 6, lane = tid & 63;
    const int n16  = lane & 15, quad = lane >> 4;
    const int img  = blockIdx.x & 7;              // XCD pin (same as loi)
    const int p0   = (blockIdx.x >> 3) << 8;      // 256-pt tile

    const float* fimg = feat + (((size_t)img) << 22);

    f32x4 acc[8][2];
    #pragma unroll
    for (int ot = 0; ot < 8; ++ot) {
        acc[ot][0] = (f32x4){0.f, 0.f, 0.f, 0.f};
        acc[ot][1] = (f32x4){0.f, 0.f, 0.f, 0.f};
    }

    // issue one K-stage (32 channels) of contiguous 1 KB rows into buf b
    auto issue = [&](int s, int b) {
        #pragma unroll
        for (int i = 0; i < 4; ++i) {
            const int cl = wv * 4 + i;            // local channel 0..31
            const int ch = s * 32 + cl;
            const float* src = fimg + (((size_t)ch) << 14) + p0 + lane * 4;
            float* dst = &u.fbuf[b][cl * 260 + (cl >> 3) * 16];  // wave-uniform base
            __builtin_amdgcn_global_load_lds(
                (const __attribute__((address_space(1))) void*)src,
                (__attribute__((address_space(3))) void*)dst, 16, 0, 0);
        }
    };

    issue(0, 0);
    __syncthreads();                               // drains vmcnt -> buf0 ready

    for (int s = 0; s < 8; ++s) {
        const int cur = s & 1;
        if (s < 7) issue(s + 1, cur ^ 1);          // prefetch next stage

        // build B-frags (x): lane(n16,quad) holds x[k=quad*8+j][pt=base+n16]
        f16x8 xf[2];
        #pragma unroll
        for (int pt = 0; pt < 2; ++pt) {
            const int pbase = wv * 32 + pt * 16 + n16;
            const float* fb = &u.fbuf[cur][quad * 16 + pbase];
            f16x8 xv;
            #pragma unroll
            for (int j = 0; j < 8; ++j)
                xv[j] = (f16)fb[(quad * 8 + j) * 260];
            xf[pt] = xv;
        }

        // A-frags (W, L2-hot): lane(n16,quad) holds W[o=ot*16+n16][k=quad*8+j]
        const f16* wrow = w16 + (size_t)n16 * 256 + s * 32 + quad * 8;
        #pragma unroll
        for (int ot = 0; ot < 8; ++ot) {
            const f16x8 wf = *(const f16x8*)(wrow + ot * 4096);
            acc[ot][0] = __builtin_amdgcn_mfma_f32_16x16x32_f16(wf, xf[0], acc[ot][0], 0, 0, 0);
            acc[ot][1] = __builtin_amdgcn_mfma_f32_16x16x32_f16(wf, xf[1], acc[ot][1], 0, 0, 0);
        }
        __syncthreads();                           // next buf ready; fbuf[cur] free
    }

    // epilogue: D[o][pt] row = quad*4+r (o), col = n16 (pt) -> LDS -> coalesced rows
    #pragma unroll
    for (int ot = 0; ot < 8; ++ot) {
        const float4 bq = *(const float4*)&bias[ot * 16 + quad * 4];
        const float bqa[4] = {bq.x, bq.y, bq.z, bq.w};
        #pragma unroll
        for (int pt = 0; pt < 2; ++pt) {
            f16x4 h;
            #pragma unroll
            for (int r = 0; r < 4; ++r) h[r] = (f16)(acc[ot][pt][r] + bqa[r]);
            *(f16x4*)&u.epi[wv * 32 + pt * 16 + n16][ot * 16 + quad * 4] = h;
        }
    }
    __syncthreads();

    #pragma unroll
    for (int it = 0; it < 8; ++it) {
        const int idx = it * 512 + tid;
        const int row = idx >> 4, seg = idx & 15;
        const float4 v = *(const float4*)&u.epi[row][seg * 8];
        *(float4*)&xmap[(((size_t)(img * 16384 + p0 + row)) << 7) + seg * 8] = v;
    }
}

// ---------------------------------------------------------------------------
// loi: 8 lines/block, image = blockIdx & 7 (XCD-pinned).
// Sampling v2: 16-B gathers (8 ch/lane, j=0..15), 4 maxpool samples split
// 2-per-lane-half (sh = (lane>>4)&1) + one shfl_xor(16) max combine.
// Halves gather instructions (128->64/thread), tuple reads (32->16) and
// interp VALU vs the 8-B version.  Per-channel arithmetic identical.
// ---------------------------------------------------------------------------
__global__ __launch_bounds__(256)
void loi_kernel(const f16*   __restrict__ x,       // [8][16384][128] f16
                const float* __restrict__ lines,
                const f16*   __restrict__ wsp,
                const float* __restrict__ bn1g, const float* __restrict__ bn1b,
                const float* __restrict__ bn1m, const float* __restrict__ bn1v,
                const float* __restrict__ b1,
                const float* __restrict__ bn2g, const float* __restrict__ bn2b,
                const float* __restrict__ bn2m, const float* __restrict__ bn2v,
                const float* __restrict__ b2,
                const float* __restrict__ bn3g, const float* __restrict__ bn3b,
                const float* __restrict__ bn3m, const float* __restrict__ bn3v,
                const float* __restrict__ b3,
                const float* __restrict__ fc2w, const float* __restrict__ fc2b,
                float* __restrict__ out) {
    __shared__ f16 xp[64][136];                       // 17408 B
    __shared__ alignas(16) union {
        struct { int toff[256][4]; f16 twgt[256][4]; } tp;     // 6144 B
        struct { f16 h1[80][72]; f16 h2[64][72]; } cv;         // 20736 B
    } u;
    __shared__ f16 s1h[128], t1h[128];                // 512 B
    __shared__ float s2f[64], t2f[64], s3f[64], t3f[64], b1f[64], b2f[64];
    __shared__ float b3f[128];
    __shared__ float wsum[4][8];

    const f16* w1f16 = wsp + 32768;
    const f16* w2f16 = wsp + 40960;
    const f16* w3f16 = wsp + 53248;

    const int tid  = threadIdx.x;
    const int wv   = tid >> 6, lane = tid & 63;
    const int n16  = lane & 15, quad = lane >> 4;
    const int img  = blockIdx.x & 7;                  // XCD swizzle
    const int mblk = blockIdx.x >> 3;                 // 0..255 within image

    // ---- LUTs ----
    if (tid < 128) {
        const float s = bn1g[tid] * rsqrtf(bn1v[tid] + EPSBN);
        s1h[tid] = (f16)s; t1h[tid] = (f16)(bn1b[tid] - bn1m[tid] * s);
    }
    if (tid < 64) {
        const float s = bn2g[tid] * rsqrtf(bn2v[tid] + EPSBN);
        s2f[tid] = s; t2f[tid] = bn2b[tid] - bn2m[tid] * s;
        b1f[tid] = b1[tid];
    } else if (tid < 128) {
        const int c = tid - 64;
        const float s = bn3g[c] * rsqrtf(bn3v[c] + EPSBN);
        s3f[c] = s; t3f[c] = bn3b[c] - bn3m[c] * s;
        b2f[c] = b2[c];
    } else {
        b3f[tid - 128] = b3[tid - 128];
    }

    // ---- interp tuples: one per (line, pt) ----
    {
        const int li = tid >> 5, pt = tid & 31;
        const int gl = img * 2048 + mblk * 8 + li;
        const float4 ln = *(const float4*)&lines[gl * 4];
        const float lam = (float)pt * (1.0f / 31.0f);
        const float px = ln.x * lam + ln.z * (1.f - lam) - 0.5f;
        const float py = ln.y * lam + ln.w * (1.f - lam) - 0.5f;
        const float px0 = fminf(fmaxf(floorf(px), 0.f), 127.f);
        const float py0 = fminf(fmaxf(floorf(py), 0.f), 127.f);
        const float px1 = fminf(px0 + 1.f, 127.f);
        const float py1 = fminf(py0 + 1.f, 127.f);
        const int ix0 = (int)px0, iy0 = (int)py0;
        const int ix1 = (int)px1, iy1 = (int)py1;
        u.tp.toff[tid][0] = (((ix0 << 7) + iy0) << 7);
        u.tp.toff[tid][1] = (((ix1 << 7) + iy0) << 7);
        u.tp.toff[tid][2] = (((ix0 << 7) + iy1) << 7);
        u.tp.toff[tid][3] = (((ix1 << 7) + iy1) << 7);
        const float wx1 = px1 - px, wx0 = px - px0;
        const float wy1 = py1 - py, wy0 = py - py0;
        u.tp.twgt[tid][0] = (f16)(wx1 * wy1); u.tp.twgt[tid][1] = (f16)(wx0 * wy1);
        u.tp.twgt[tid][2] = (f16)(wx1 * wy0); u.tp.twgt[tid][3] = (f16)(wx0 * wy0);
    }
    __syncthreads();   // B1

    // ---- sampling + maxpool: 8 ch/lane (16 B gathers), 2 samples/lane-half,
    //      shfl_xor(16) final max ----
    {
        const int h  = lane >> 5;            // line parity within wave
        const int sh = (lane >> 4) & 1;      // which half of the 4 pool samples
        const int j  = lane & 15;            // 8-channel group
        const int li = wv * 2 + h;
        const f16* xbh = x + (((size_t)img) << 21) + 8 * j;
        #pragma unroll
        for (int t = 0; t < 8; ++t) {
            f16x8 m;
            #pragma unroll
            for (int q = 0; q < 8; ++q) m[q] = (f16)(-60000.f);
            #pragma unroll
            for (int ss = 0; ss < 2; ++ss) {
                const int combo = li * 32 + t * 4 + sh * 2 + ss;
                const int4  off = *(const int4*)&u.tp.toff[combo][0];
                const f16x4 tw  = *(const f16x4*)&u.tp.twgt[combo][0];
                const f16x8 g00 = *(const f16x8*)(xbh + off.x);
                const f16x8 g10 = *(const f16x8*)(xbh + off.y);
                const f16x8 g01 = *(const f16x8*)(xbh + off.z);
                const f16x8 g11 = *(const f16x8*)(xbh + off.w);
                f16x8 w0, w1v, w2v, w3v;
                #pragma unroll
                for (int q = 0; q < 8; ++q) {
                    w0[q] = tw[0]; w1v[q] = tw[1]; w2v[q] = tw[2]; w3v[q] = tw[3];
                }
                const f16x8 v = g00 * w0 + g10 * w1v + g01 * w2v + g11 * w3v;
                m = hmax8(m, v);
            }
            union { f16x8 v8; int i4[4]; } cv;
            cv.v8 = m;
            #pragma unroll
            for (int q = 0; q < 4; ++q) cv.i4[q] = __shfl_xor(cv.i4[q], 16, 64);
            m = hmax8(m, cv.v8);
            if (sh == 0) *(f16x8*)&xp[li * 8 + t][8 * j] = m;
        }
    }
    __syncthreads();   // B2 (tuples dead; xp ready)

    // ---- zero h1 guard rows ----
    {
        const int r = tid >> 4, seg = tid & 15;
        const int row = (r >> 1) * 10 + (r & 1) * 9;
        *(unsigned long long*)&u.cv.h1[row][seg * 4] = 0ull;
    }

    // ---- conv1 + fused bn1/relu (packed f16) ----
    {
        const int o_lane = wv * 16 + n16;
        f32x4 acc1[4];
        #pragma unroll
        for (int nt = 0; nt < 4; ++nt) acc1[nt] = (f32x4){0.f, 0.f, 0.f, 0.f};
        #pragma unroll
        for (int ks = 0; ks < 4; ++ks) {
            const int k = ks * 32 + quad * 8;
            const f16x8 a  = *(const f16x8*)&w1f16[o_lane * 128 + k];
            const f16x8 s8 = *(const f16x8*)&s1h[k];
            const f16x8 t8 = *(const f16x8*)&t1h[k];
            #pragma unroll
            for (int nt = 0; nt < 4; ++nt) {
                const f16x8 raw = *(const f16x8*)&xp[nt * 16 + n16][k];
                const f16x8 bf = relu8(raw * s8 + t8);
                acc1[nt] = __builtin_amdgcn_mfma_f32_16x16x32_f16(a, bf, acc1[nt], 0, 0, 0);
            }
        }
        #pragma unroll
        for (int nt = 0; nt < 4; ++nt) {
            const int n = nt * 16 + n16;
            const int nprow = (n >> 3) * 10 + (n & 7) + 1;
            #pragma unroll
            for (int r = 0; r < 4; ++r) {
                const int o = wv * 16 + quad * 4 + r;
                const float v = fmaxf((acc1[nt][r] + b1f[o]) * s2f[o] + t2f[o], 0.f);
                u.cv.h1[nprow][o] = (f16)v;
            }
        }
    }
    __syncthreads();   // B3

    // ---- conv2: 3 shifted [64x64] matmuls ----
    {
        const int o_lane = wv * 16 + n16;
        f32x4 acc2[4];
        #pragma unroll
        for (int nt = 0; nt < 4; ++nt) acc2[nt] = (f32x4){0.f, 0.f, 0.f, 0.f};
        #pragma unroll
        for (int d = 0; d < 3; ++d) {
            const f16* A2 = w2f16 + d * 4096;
            #pragma unroll
            for (int ks = 0; ks < 2; ++ks) {
                const int k = ks * 32 + quad * 8;
                const f16x8 a = *(const f16x8*)&A2[o_lane * 64 + k];
                #pragma unroll
                for (int nt = 0; nt < 4; ++nt) {
                    const int n = nt * 16 + n16;
                    const int row = (n >> 3) * 10 + (n & 7) + d;
                    const f16x8 bf = *(const f16x8*)&u.cv.h1[row][k];
                    acc2[nt] = __builtin_amdgcn_mfma_f32_16x16x32_f16(a, bf, acc2[nt], 0, 0, 0);
                }
            }
        }
        #pragma unroll
        for (int nt = 0; nt < 4; ++nt) {
            const int n = nt * 16 + n16;
            #pragma unroll
            for (int r = 0; r < 4; ++r) {
                const int o = wv * 16 + quad * 4 + r;
                const float v = fmaxf((acc2[nt][r] + b2f[o]) * s3f[o] + t3f[o], 0.f);
                u.cv.h2[n][o] = (f16)v;
            }
        }
    }
    __syncthreads();   // B4

    // ---- conv3 + residual + relu + fc2 ----
    {
        // per-lane fc2 weights: (n&7) == n16&7 is lane-constant -> 8 scalars
        const int col = n16 & 7, obase = wv * 16 + quad * 4;
        float fcv[2][4];
        #pragma unroll
        for (int h = 0; h < 2; ++h)
            #pragma unroll
            for (int r = 0; r < 4; ++r)
                fcv[h][r] = fc2w[(h * 64 + obase + r) * 8 + col];

        f32x4 acc3[2][4];
        #pragma unroll
        for (int h = 0; h < 2; ++h)
            #pragma unroll
            for (int nt = 0; nt < 4; ++nt) acc3[h][nt] = (f32x4){0.f, 0.f, 0.f, 0.f};
        #pragma unroll
        for (int ks = 0; ks < 2; ++ks) {
            const int k = ks * 32 + quad * 8;
            const f16x8 a0 = *(const f16x8*)&w3f16[(wv * 16 + n16) * 64 + k];
            const f16x8 a1 = *(const f16x8*)&w3f16[(64 + wv * 16 + n16) * 64 + k];
            #pragma unroll
            for (int nt = 0; nt < 4; ++nt) {
                const f16x8 bf = *(const f16x8*)&u.cv.h2[nt * 16 + n16][k];
                acc3[0][nt] = __builtin_amdgcn_mfma_f32_16x16x32_f16(a0, bf, acc3[0][nt], 0, 0, 0);
                acc3[1][nt] = __builtin_amdgcn_mfma_f32_16x16x32_f16(a1, bf, acc3[1][nt], 0, 0, 0);
            }
        }
        float part[4] = {0.f, 0.f, 0.f, 0.f};
        #pragma unroll
        for (int h = 0; h < 2; ++h) {
            const float4 bq = *(const float4*)&b3f[h * 64 + obase];
            const float bqa[4] = {bq.x, bq.y, bq.z, bq.w};
            #pragma unroll
            for (int nt = 0; nt < 4; ++nt) {
                const int n = nt * 16 + n16;
                const f16x4 rx = *(const f16x4*)&xp[n][h * 64 + obase];
                float p = 0.f;
                #pragma unroll
                for (int r = 0; r < 4; ++r) {
                    float v = acc3[h][nt][r] + bqa[r] + (float)rx[r];
                    v = fmaxf(v, 0.f);
                    p += v * fcv[h][r];
                }
                part[nt] += p;
            }
        }
        #pragma unroll
        for (int off_i = 0; off_i < 5; ++off_i) {
            const int off = (int[]){1, 2, 4, 16, 32}[off_i];
            part[0] += __shfl_xor(part[0], off, 64);
            part[1] += __shfl_xor(part[1], off, 64);
            part[2] += __shfl_xor(part[2], off, 64);
            part[3] += __shfl_xor(part[3], off, 64);
        }
        if ((lane & 55) == 0) {          // lanes 0 and 8
            const int par = (lane >> 3) & 1;
            wsum[wv][0 + par] = part[0];
            wsum[wv][2 + par] = part[1];
            wsum[wv][4 + par] = part[2];
            wsum[wv][6 + par] = part[3];
        }
    }
    __syncthreads();   // B5

    if (tid < 8) {
        const float s = wsum[0][tid] + wsum[1][tid] + wsum[2][tid] + wsum[3][tid];
        out[img * 2048 + mblk * 8 + tid] = s + fc2b[0];
    }
}

// ---------------------------------------------------------------------------
extern "C" void kernel_launch(void* const* d_in, const int* in_sizes, int n_in,
                              void* d_out, int out_size, void* d_ws, size_t ws_size,
                              hipStream_t stream) {
    const float* feature = (const float*)d_in[0];
    const float* lines   = (const float*)d_in[1];
    const float* fc1_w   = (const float*)d_in[2];
    const float* fc1_b   = (const float*)d_in[3];
    const float* bn1g    = (const float*)d_in[4];
    const float* bn1b    = (const float*)d_in[5];
    const float* bn1m    = (const float*)d_in[6];
    const float* bn1v    = (const float*)d_in[7];
    const float* w1      = (const float*)d_in[8];
    const float* b1      = (const float*)d_in[9];
    const float* bn2g    = (const float*)d_in[10];
    const float* bn2b    = (const float*)d_in[11];
    const float* bn2m    = (const float*)d_in[12];
    const float* bn2v    = (const float*)d_in[13];
    const float* w2      = (const float*)d_in[14];
    const float* b2      = (const float*)d_in[15];
    const float* bn3g    = (const float*)d_in[16];
    const float* bn3b    = (const float*)d_in[17];
    const float* bn3m    = (const float*)d_in[18];
    const float* bn3v    = (const float*)d_in[19];
    const float* w3      = (const float*)d_in[20];
    const float* b3      = (const float*)d_in[21];
    const float* fc2w    = (const float*)d_in[22];
    const float* fc2b    = (const float*)d_in[23];

    f16* xmap = (f16*)d_ws;                                      // 32 MiB
    f16* wsp  = (f16*)((char*)d_ws + (size_t)32 * 1024 * 1024);  // 120 KiB

    wprep_kernel<<<240, 256, 0, stream>>>(fc1_w, w1, w2, w3, wsp);
    fc1_mfma<<<512, 512, 0, stream>>>(feature, wsp, fc1_b, xmap);
    loi_kernel<<<2048, 256, 0, stream>>>(xmap, lines, wsp,
                                         bn1g, bn1b, bn1m, bn1v, b1,
                                         bn2g, bn2b, bn2m, bn2v, b2,
                                         bn3g, bn3b, bn3m, bn3v, b3,
                                         fc2w, fc2b, (float*)d_out);
}

// Round 5
// 281.863 us; speedup vs baseline: 1.0734x; 1.0131x over previous
//
#include <hip/hip_runtime.h>

#define EPSBN 1e-5f

typedef _Float16 f16;
typedef _Float16 f16x8 __attribute__((ext_vector_type(8)));
typedef _Float16 f16x4 __attribute__((ext_vector_type(4)));
typedef _Float16 f16x2 __attribute__((ext_vector_type(2)));
typedef float    f32x4 __attribute__((ext_vector_type(4)));

#define AS1 __attribute__((address_space(1)))
#define AS3 __attribute__((address_space(3)))

__device__ inline f16x8 hmax8(f16x8 a, f16x8 b) {
    f16x8 r;
    #pragma unroll
    for (int i = 0; i < 8; ++i) r[i] = a[i] > b[i] ? a[i] : b[i];
    return r;
}
__device__ inline f16x8 relu8(f16x8 v) {
    f16x8 r;
    #pragma unroll
    for (int i = 0; i < 8; ++i) r[i] = v[i] > (f16)0.f ? v[i] : (f16)0.f;
    return r;
}

// ---------------------------------------------------------------------------
// wprep: weights -> f16.
// region0 [0,32768): fc1 W in FRAGMENT order wfrag[s(8)][l(64)][otg(8)][k8(8)]
//   value = fc1w[o=otg*16+(l&15)][k = s*32 + (l>>4)*8 + k8]
// w1 [32768,40960) ; w2 as [tau][o][i] [40960,53248) ; w3 [53248,61440)
// ---------------------------------------------------------------------------
__global__ void wprep_kernel(const float* __restrict__ fc1w,
                             const float* __restrict__ w1,
                             const float* __restrict__ w2,
                             const float* __restrict__ w3,
                             f16* __restrict__ dst) {
    const int i = blockIdx.x * 256 + threadIdx.x;   // 61440 total
    float v;
    if (i < 32768) {
        const int k8 = i & 7, otg = (i >> 3) & 7, l = (i >> 6) & 63, s = i >> 12;
        const int n16l = l & 15, quadl = l >> 4;
        v = fc1w[(otg * 16 + n16l) * 256 + s * 32 + quadl * 8 + k8];
    }
    else if (i < 40960) v = w1[i - 32768];
    else if (i < 53248) {
        const int j = i - 40960, tau = j >> 12, rest = j & 4095;
        v = w2[rest * 3 + tau];
    } else              v = w3[i - 53248];
    dst[i] = (f16)v;
}

// ---------------------------------------------------------------------------
// fc1 v4: pure-DMA counted-vmcnt pipeline.
//   - W in LDS (64 KB, fragment-linear, DMA'd once in prologue) -> the K-loop
//     has ZERO vmem except the staging DMA (v3's failure mode eliminated).
//   - 1024 thr/block, grid 512 (1 blk/CU, 16 waves = 4/SIMD, same as v2).
//   - ring of 4 x 16-ch slots (16 KB each, unpadded); rows 8-15 XOR-swizzled
//     on the GLOBAL source (chunk ^ 4), inverse-XOR on read (rule #21) ->
//     2-way banks, total LDS exactly 128 KB.
//   - raw s_barrier + s_waitcnt vmcnt(2) (vmcnt(0) only last iter): 2-4
//     half-stages (33-67 KB/CU) continuously in flight, never drained.
// ---------------------------------------------------------------------------
__global__ __launch_bounds__(1024, 4)
void fc1_mfma(const float* __restrict__ feat,   // [8][256][16384] f32
              const f16*   __restrict__ wfrag,  // [8][64][8][8] f16 (pre-swizzled)
              const float* __restrict__ bias,   // [128]
              f16*         __restrict__ xmap) { // [8][16384][128] f16
    __shared__ f16 wlds[32768];                  // 64 KB
    __shared__ union {
        float ring[4][4096];                     // 64 KB: 4 slots x 16 ch x 1 KB
        f16   epi[128][136];                     // 34,816 B (epilogue staging)
    } u;

    const int tid  = threadIdx.x;
    const int wv   = tid >> 6;                   // 0..15
    const int lane = tid & 63;
    const int n16  = lane & 15, quad = lane >> 4;
    const int pw   = wv >> 1;                    // pt-tile 0..7 (32 pts each)
    const int ow   = wv & 1;                     // o-half (64 outputs)
    const int img  = blockIdx.x & 7;             // XCD pin (same as loi)
    const int p0   = (blockIdx.x >> 3) << 8;     // 256-pt tile

    const float* fimg = feat + (((size_t)img) << 22);

    f32x4 acc[2][4];
    #pragma unroll
    for (int ptg = 0; ptg < 2; ++ptg)
        #pragma unroll
        for (int t = 0; t < 4; ++t) acc[ptg][t] = (f32x4){0.f, 0.f, 0.f, 0.f};

    // one half-stage = 16 channels; wave wv DMAs local row wv (1 KB).
    // rows 8-15: source chunk XOR 4 (both-sides swizzle with linear LDS dest).
    const int swz = (wv >> 3) << 2;              // 0 for rows 0-7, 4 for 8-15
    auto issue_hs = [&](int h) {
        const int ch = h * 16 + wv;
        const float* src = fimg + (((size_t)ch) << 14) + p0 + ((lane ^ swz) << 2);
        float* dst = u.ring[h & 3] + (wv << 8);  // wave-uniform, linear
        __builtin_amdgcn_global_load_lds((const AS1 void*)src,
                                         (AS3 void*)dst, 16, 0, 0);
    };

    // ---- prologue: 4 W chunks + half-stages 0..3 (8 DMA/wave) ----
    #pragma unroll
    for (int c4 = 0; c4 < 4; ++c4) {
        const int c = wv + 16 * c4;              // 64 chunks of 1 KB
        __builtin_amdgcn_global_load_lds((const AS1 void*)(wfrag + c * 512 + lane * 8),
                                         (AS3 void*)(wlds + c * 512), 16, 0, 0);
    }
    #pragma unroll
    for (int h = 0; h < 4; ++h) issue_hs(h);

    // per-lane read column within a slot row (inverse swizzle):
    // pt = pw*32 + ptg*16 + n16 ; rows 8-15 are chunk^4 ; quad&1 picks rows 0-7/8-15
    const int xswz = (quad & 1) << 2;

    #pragma unroll
    for (int s = 0; s < 8; ++s) {
        if (s < 7) asm volatile("s_waitcnt vmcnt(2)" ::: "memory");
        else       asm volatile("s_waitcnt vmcnt(0)" ::: "memory");
        __builtin_amdgcn_s_barrier();
        __builtin_amdgcn_sched_barrier(0);

        // W fragments (lgkm only): wlds[((s*64+lane)*8 + ow*4 + t)*8]
        f16x8 wf[4];
        #pragma unroll
        for (int t = 0; t < 4; ++t)
            wf[t] = *(const f16x8*)&wlds[((s * 64 + lane) * 8 + ow * 4 + t) * 8];

        // x fragments: k = quad*8+j ; quad>>1 picks slot (hs 2s / 2s+1),
        // quad&1 picks row-half; col inverse-XOR'd for rows 8-15.
        f16x8 xf[2];
        #pragma unroll
        for (int ptg = 0; ptg < 2; ++ptg) {
            const int pt   = pw * 32 + ptg * 16 + n16;
            const int col  = ((((pt >> 2) ^ xswz) << 2) | (pt & 3));
            const float* fb = u.ring[(2 * s + (quad >> 1)) & 3]
                              + ((quad & 1) << 11) + col;     // (quad&1)*8 rows * 256
            f16x8 xv;
            #pragma unroll
            for (int j = 0; j < 8; ++j) xv[j] = (f16)fb[j << 8];
            xf[ptg] = xv;
        }

        #pragma unroll
        for (int ptg = 0; ptg < 2; ++ptg)
            #pragma unroll
            for (int t = 0; t < 4; ++t)
                acc[ptg][t] = __builtin_amdgcn_mfma_f32_16x16x32_f16(wf[t], xf[ptg],
                                                                     acc[ptg][t], 0, 0, 0);

        __builtin_amdgcn_sched_barrier(0);
        __builtin_amdgcn_s_barrier();            // all waves done reading slots
        __builtin_amdgcn_sched_barrier(0);
        if (s < 6) { issue_hs(2 * s + 4); issue_hs(2 * s + 5); }
    }

    // ---- epilogue: 2 passes of 128 rows through u.epi ----
    #pragma unroll
    for (int P = 0; P < 2; ++P) {
        __syncthreads();
        if ((pw >> 2) == P) {
            #pragma unroll
            for (int ptg = 0; ptg < 2; ++ptg) {
                const int rowl = (pw & 3) * 32 + ptg * 16 + n16;
                #pragma unroll
                for (int t = 0; t < 4; ++t) {
                    const int o = ow * 64 + t * 16 + quad * 4;
                    const float4 bq = *(const float4*)&bias[o];
                    f16x4 hv;
                    hv[0] = (f16)(acc[ptg][t][0] + bq.x);
                    hv[1] = (f16)(acc[ptg][t][1] + bq.y);
                    hv[2] = (f16)(acc[ptg][t][2] + bq.z);
                    hv[3] = (f16)(acc[ptg][t][3] + bq.w);
                    *(f16x4*)&u.epi[rowl][o] = hv;
                }
            }
        }
        __syncthreads();
        #pragma unroll
        for (int it = 0; it < 2; ++it) {
            const int idx = it * 1024 + tid;
            const int rowl = idx >> 4, seg = idx & 15;
            const float4 v = *(const float4*)&u.epi[rowl][seg * 8];
            *(float4*)&xmap[(((size_t)(img * 16384 + p0 + P * 128 + rowl)) << 7) + seg * 8] = v;
        }
    }
}

// ---------------------------------------------------------------------------
// loi: unchanged from round 4 (63.5 us).  8 lines/block, XCD-pinned gathers,
// 16-B gathers (8 ch/lane), pool samples split across lane-halves +
// shfl_xor(16) max, conv1/conv2/conv3 MFMA, residual+relu+fc2.
// ---------------------------------------------------------------------------
__global__ __launch_bounds__(256)
void loi_kernel(const f16*   __restrict__ x,       // [8][16384][128] f16
                const float* __restrict__ lines,
                const f16*   __restrict__ wsp,
                const float* __restrict__ bn1g, const float* __restrict__ bn1b,
                const float* __restrict__ bn1m, const float* __restrict__ bn1v,
                const float* __restrict__ b1,
                const float* __restrict__ bn2g, const float* __restrict__ bn2b,
                const float* __restrict__ bn2m, const float* __restrict__ bn2v,
                const float* __restrict__ b2,
                const float* __restrict__ bn3g, const float* __restrict__ bn3b,
                const float* __restrict__ bn3m, const float* __restrict__ bn3v,
                const float* __restrict__ b3,
                const float* __restrict__ fc2w, const float* __restrict__ fc2b,
                float* __restrict__ out) {
    __shared__ f16 xp[64][136];                       // 17408 B
    __shared__ alignas(16) union {
        struct { int toff[256][4]; f16 twgt[256][4]; } tp;     // 6144 B
        struct { f16 h1[80][72]; f16 h2[64][72]; } cv;         // 20736 B
    } u;
    __shared__ f16 s1h[128], t1h[128];                // 512 B
    __shared__ float s2f[64], t2f[64], s3f[64], t3f[64], b1f[64], b2f[64];
    __shared__ float b3f[128];
    __shared__ float wsum[4][8];

    const f16* w1f16 = wsp + 32768;
    const f16* w2f16 = wsp + 40960;
    const f16* w3f16 = wsp + 53248;

    const int tid  = threadIdx.x;
    const int wv   = tid >> 6, lane = tid & 63;
    const int n16  = lane & 15, quad = lane >> 4;
    const int img  = blockIdx.x & 7;                  // XCD swizzle
    const int mblk = blockIdx.x >> 3;                 // 0..255 within image

    // ---- LUTs ----
    if (tid < 128) {
        const float s = bn1g[tid] * rsqrtf(bn1v[tid] + EPSBN);
        s1h[tid] = (f16)s; t1h[tid] = (f16)(bn1b[tid] - bn1m[tid] * s);
    }
    if (tid < 64) {
        const float s = bn2g[tid] * rsqrtf(bn2v[tid] + EPSBN);
        s2f[tid] = s; t2f[tid] = bn2b[tid] - bn2m[tid] * s;
        b1f[tid] = b1[tid];
    } else if (tid < 128) {
        const int c = tid - 64;
        const float s = bn3g[c] * rsqrtf(bn3v[c] + EPSBN);
        s3f[c] = s; t3f[c] = bn3b[c] - bn3m[c] * s;
        b2f[c] = b2[c];
    } else {
        b3f[tid - 128] = b3[tid - 128];
    }

    // ---- interp tuples: one per (line, pt) ----
    {
        const int li = tid >> 5, pt = tid & 31;
        const int gl = img * 2048 + mblk * 8 + li;
        const float4 ln = *(const float4*)&lines[gl * 4];
        const float lam = (float)pt * (1.0f / 31.0f);
        const float px = ln.x * lam + ln.z * (1.f - lam) - 0.5f;
        const float py = ln.y * lam + ln.w * (1.f - lam) - 0.5f;
        const float px0 = fminf(fmaxf(floorf(px), 0.f), 127.f);
        const float py0 = fminf(fmaxf(floorf(py), 0.f), 127.f);
        const float px1 = fminf(px0 + 1.f, 127.f);
        const float py1 = fminf(py0 + 1.f, 127.f);
        const int ix0 = (int)px0, iy0 = (int)py0;
        const int ix1 = (int)px1, iy1 = (int)py1;
        u.tp.toff[tid][0] = (((ix0 << 7) + iy0) << 7);
        u.tp.toff[tid][1] = (((ix1 << 7) + iy0) << 7);
        u.tp.toff[tid][2] = (((ix0 << 7) + iy1) << 7);
        u.tp.toff[tid][3] = (((ix1 << 7) + iy1) << 7);
        const float wx1 = px1 - px, wx0 = px - px0;
        const float wy1 = py1 - py, wy0 = py - py0;
        u.tp.twgt[tid][0] = (f16)(wx1 * wy1); u.tp.twgt[tid][1] = (f16)(wx0 * wy1);
        u.tp.twgt[tid][2] = (f16)(wx1 * wy0); u.tp.twgt[tid][3] = (f16)(wx0 * wy0);
    }
    __syncthreads();   // B1

    // ---- sampling + maxpool: 8 ch/lane (16 B gathers), 2 samples/lane-half,
    //      shfl_xor(16) final max ----
    {
        const int h  = lane >> 5;            // line parity within wave
        const int sh = (lane >> 4) & 1;      // which half of the 4 pool samples
        const int j  = lane & 15;            // 8-channel group
        const int li = wv * 2 + h;
        const f16* xbh = x + (((size_t)img) << 21) + 8 * j;
        #pragma unroll
        for (int t = 0; t < 8; ++t) {
            f16x8 m;
            #pragma unroll
            for (int q = 0; q < 8; ++q) m[q] = (f16)(-60000.f);
            #pragma unroll
            for (int ss = 0; ss < 2; ++ss) {
                const int combo = li * 32 + t * 4 + sh * 2 + ss;
                const int4  off = *(const int4*)&u.tp.toff[combo][0];
                const f16x4 tw  = *(const f16x4*)&u.tp.twgt[combo][0];
                const f16x8 g00 = *(const f16x8*)(xbh + off.x);
                const f16x8 g10 = *(const f16x8*)(xbh + off.y);
                const f16x8 g01 = *(const f16x8*)(xbh + off.z);
                const f16x8 g11 = *(const f16x8*)(xbh + off.w);
                f16x8 w0, w1v, w2v, w3v;
                #pragma unroll
                for (int q = 0; q < 8; ++q) {
                    w0[q] = tw[0]; w1v[q] = tw[1]; w2v[q] = tw[2]; w3v[q] = tw[3];
                }
                const f16x8 v = g00 * w0 + g10 * w1v + g01 * w2v + g11 * w3v;
                m = hmax8(m, v);
            }
            union { f16x8 v8; int i4[4]; } cv;
            cv.v8 = m;
            #pragma unroll
            for (int q = 0; q < 4; ++q) cv.i4[q] = __shfl_xor(cv.i4[q], 16, 64);
            m = hmax8(m, cv.v8);
            if (sh == 0) *(f16x8*)&xp[li * 8 + t][8 * j] = m;
        }
    }
    __syncthreads();   // B2 (tuples dead; xp ready)

    // ---- zero h1 guard rows ----
    {
        const int r = tid >> 4, seg = tid & 15;
        const int row = (r >> 1) * 10 + (r & 1) * 9;
        *(unsigned long long*)&u.cv.h1[row][seg * 4] = 0ull;
    }

    // ---- conv1 + fused bn1/relu (packed f16) ----
    {
        const int o_lane = wv * 16 + n16;
        f32x4 acc1[4];
        #pragma unroll
        for (int nt = 0; nt < 4; ++nt) acc1[nt] = (f32x4){0.f, 0.f, 0.f, 0.f};
        #pragma unroll
        for (int ks = 0; ks < 4; ++ks) {
            const int k = ks * 32 + quad * 8;
            const f16x8 a  = *(const f16x8*)&w1f16[o_lane * 128 + k];
            const f16x8 s8 = *(const f16x8*)&s1h[k];
            const f16x8 t8 = *(const f16x8*)&t1h[k];
            #pragma unroll
            for (int nt = 0; nt < 4; ++nt) {
                const f16x8 raw = *(const f16x8*)&xp[nt * 16 + n16][k];
                const f16x8 bf = relu8(raw * s8 + t8);
                acc1[nt] = __builtin_amdgcn_mfma_f32_16x16x32_f16(a, bf, acc1[nt], 0, 0, 0);
            }
        }
        #pragma unroll
        for (int nt = 0; nt < 4; ++nt) {
            const int n = nt * 16 + n16;
            const int nprow = (n >> 3) * 10 + (n & 7) + 1;
            #pragma unroll
            for (int r = 0; r < 4; ++r) {
                const int o = wv * 16 + quad * 4 + r;
                const float v = fmaxf((acc1[nt][r] + b1f[o]) * s2f[o] + t2f[o], 0.f);
                u.cv.h1[nprow][o] = (f16)v;
            }
        }
    }
    __syncthreads();   // B3

    // ---- conv2: 3 shifted [64x64] matmuls ----
    {
        const int o_lane = wv * 16 + n16;
        f32x4 acc2[4];
        #pragma unroll
        for (int nt = 0; nt < 4; ++nt) acc2[nt] = (f32x4){0.f, 0.f, 0.f, 0.f};
        #pragma unroll
        for (int d = 0; d < 3; ++d) {
            const f16* A2 = w2f16 + d * 4096;
            #pragma unroll
            for (int ks = 0; ks < 2; ++ks) {
                const int k = ks * 32 + quad * 8;
                const f16x8 a = *(const f16x8*)&A2[o_lane * 64 + k];
                #pragma unroll
                for (int nt = 0; nt < 4; ++nt) {
                    const int n = nt * 16 + n16;
                    const int row = (n >> 3) * 10 + (n & 7) + d;
                    const f16x8 bf = *(const f16x8*)&u.cv.h1[row][k];
                    acc2[nt] = __builtin_amdgcn_mfma_f32_16x16x32_f16(a, bf, acc2[nt], 0, 0, 0);
                }
            }
        }
        #pragma unroll
        for (int nt = 0; nt < 4; ++nt) {
            const int n = nt * 16 + n16;
            #pragma unroll
            for (int r = 0; r < 4; ++r) {
                const int o = wv * 16 + quad * 4 + r;
                const float v = fmaxf((acc2[nt][r] + b2f[o]) * s3f[o] + t3f[o], 0.f);
                u.cv.h2[n][o] = (f16)v;
            }
        }
    }
    __syncthreads();   // B4

    // ---- conv3 + residual + relu + fc2 ----
    {
        const int col = n16 & 7, obase = wv * 16 + quad * 4;
        float fcv[2][4];
        #pragma unroll
        for (int h = 0; h < 2; ++h)
            #pragma unroll
            for (int r = 0; r < 4; ++r)
                fcv[h][r] = fc2w[(h * 64 + obase + r) * 8 + col];

        f32x4 acc3[2][4];
        #pragma unroll
        for (int h = 0; h < 2; ++h)
            #pragma unroll
            for (int nt = 0; nt < 4; ++nt) acc3[h][nt] = (f32x4){0.f, 0.f, 0.f, 0.f};
        #pragma unroll
        for (int ks = 0; ks < 2; ++ks) {
            const int k = ks * 32 + quad * 8;
            const f16x8 a0 = *(const f16x8*)&w3f16[(wv * 16 + n16) * 64 + k];
            const f16x8 a1 = *(const f16x8*)&w3f16[(64 + wv * 16 + n16) * 64 + k];
            #pragma unroll
            for (int nt = 0; nt < 4; ++nt) {
                const f16x8 bf = *(const f16x8*)&u.cv.h2[nt * 16 + n16][k];
                acc3[0][nt] = __builtin_amdgcn_mfma_f32_16x16x32_f16(a0, bf, acc3[0][nt], 0, 0, 0);
                acc3[1][nt] = __builtin_amdgcn_mfma_f32_16x16x32_f16(a1, bf, acc3[1][nt], 0, 0, 0);
            }
        }
        float part[4] = {0.f, 0.f, 0.f, 0.f};
        #pragma unroll
        for (int h = 0; h < 2; ++h) {
            const float4 bq = *(const float4*)&b3f[h * 64 + obase];
            const float bqa[4] = {bq.x, bq.y, bq.z, bq.w};
            #pragma unroll
            for (int nt = 0; nt < 4; ++nt) {
                const int n = nt * 16 + n16;
                const f16x4 rx = *(const f16x4*)&xp[n][h * 64 + obase];
                float p = 0.f;
                #pragma unroll
                for (int r = 0; r < 4; ++r) {
                    float v = acc3[h][nt][r] + bqa[r] + (float)rx[r];
                    v = fmaxf(v, 0.f);
                    p += v * fcv[h][r];
                }
                part[nt] += p;
            }
        }
        #pragma unroll
        for (int off_i = 0; off_i < 5; ++off_i) {
            const int off = (int[]){1, 2, 4, 16, 32}[off_i];
            part[0] += __shfl_xor(part[0], off, 64);
            part[1] += __shfl_xor(part[1], off, 64);
            part[2] += __shfl_xor(part[2], off, 64);
            part[3] += __shfl_xor(part[3], off, 64);
        }
        if ((lane & 55) == 0) {          // lanes 0 and 8
            const int par = (lane >> 3) & 1;
            wsum[wv][0 + par] = part[0];
            wsum[wv][2 + par] = part[1];
            wsum[wv][4 + par] = part[2];
            wsum[wv][6 + par] = part[3];
        }
    }
    __syncthreads();   // B5

    if (tid < 8) {
        const float s = wsum[0][tid] + wsum[1][tid] + wsum[2][tid] + wsum[3][tid];
        out[img * 2048 + mblk * 8 + tid] = s + fc2b[0];
    }
}

// ---------------------------------------------------------------------------
extern "C" void kernel_launch(void* const* d_in, const int* in_sizes, int n_in,
                              void* d_out, int out_size, void* d_ws, size_t ws_size,
                              hipStream_t stream) {
    const float* feature = (const float*)d_in[0];
    const float* lines   = (const float*)d_in[1];
    const float* fc1_w   = (const float*)d_in[2];
    const float* fc1_b   = (const float*)d_in[3];
    const float* bn1g    = (const float*)d_in[4];
    const float* bn1b    = (const float*)d_in[5];
    const float* bn1m    = (const float*)d_in[6];
    const float* bn1v    = (const float*)d_in[7];
    const float* w1      = (const float*)d_in[8];
    const float* b1      = (const float*)d_in[9];
    const float* bn2g    = (const float*)d_in[10];
    const float* bn2b    = (const float*)d_in[11];
    const float* bn2m    = (const float*)d_in[12];
    const float* bn2v    = (const float*)d_in[13];
    const float* w2      = (const float*)d_in[14];
    const float* b2      = (const float*)d_in[15];
    const float* bn3g    = (const float*)d_in[16];
    const float* bn3b    = (const float*)d_in[17];
    const float* bn3m    = (const float*)d_in[18];
    const float* bn3v    = (const float*)d_in[19];
    const float* w3      = (const float*)d_in[20];
    const float* b3      = (const float*)d_in[21];
    const float* fc2w    = (const float*)d_in[22];
    const float* fc2b    = (const float*)d_in[23];

    f16* xmap = (f16*)d_ws;                                      // 32 MiB
    f16* wsp  = (f16*)((char*)d_ws + (size_t)32 * 1024 * 1024);  // 120 KiB

    wprep_kernel<<<240, 256, 0, stream>>>(fc1_w, w1, w2, w3, wsp);
    fc1_mfma<<<512, 1024, 0, stream>>>(feature, wsp, fc1_b, xmap);
    loi_kernel<<<2048, 256, 0, stream>>>(xmap, lines, wsp,
                                         bn1g, bn1b, bn1m, bn1v, b1,
                                         bn2g, bn2b, bn2m, bn2v, b2,
                                         bn3g, bn3b, bn3m, bn3v, b3,
                                         fc2w, fc2b, (float*)d_out);
}